// Round 6
// baseline (399.724 us; speedup 1.0000x reference)
//
#include <hip/hip_runtime.h>

// ---------------------------------------------------------------------------
// SelfAttention block: x @ W_qkv -> RoPE(q,k) -> flash attention -> @ W_proj
// B=2, S=2048, D=2048, H=16, hd=128.  All matmuls in bf16 MFMA (fp32 accum).
// GEMMs: 256-wide tiles, BK=32, 4-buffer LDS, depth-3 counted-vmcnt pipeline
// (raw s_barrier, never vmcnt(0) in the main loop).
// ---------------------------------------------------------------------------

typedef __attribute__((ext_vector_type(4))) float  f32x4;
typedef __attribute__((ext_vector_type(8))) short  short8;
typedef __attribute__((ext_vector_type(4))) float  fv4;
typedef __attribute__((ext_vector_type(4))) unsigned short us4;

#define MFMA16(accv, av, bv) \
  asm volatile("v_mfma_f32_16x16x32_bf16 %0, %1, %2, %0" : "+v"(accv) : "v"(av), "v"(bv))

__device__ __forceinline__ unsigned short f2bf(float f) {
  unsigned int u = __float_as_uint(f);
  u += 0x7fffu + ((u >> 16) & 1u);      // round-to-nearest-even
  return (unsigned short)(u >> 16);
}

__device__ __forceinline__ void gl_lds16(const void* g, void* l) {
  // async global->LDS, 16B per lane; LDS dest = uniform base + lane*16
  __builtin_amdgcn_global_load_lds((const __attribute__((address_space(1))) void*)g,
                                   (__attribute__((address_space(3))) void*)l, 16, 0, 0);
}

// ---------------------------------------------------------------------------
// Prep: fp32 -> bf16 convert (x), and fp32 -> transposed bf16 (weights)
// ---------------------------------------------------------------------------
__global__ void cvt_f32_bf16(const float* __restrict__ in,
                             unsigned short* __restrict__ out, int n4) {
  int i = blockIdx.x * blockDim.x + threadIdx.x;
  int stride = gridDim.x * blockDim.x;
  for (; i < n4; i += stride) {
    fv4 v = ((const fv4*)in)[i];
    us4 o;
    o[0] = f2bf(v[0]); o[1] = f2bf(v[1]); o[2] = f2bf(v[2]); o[3] = f2bf(v[3]);
    ((us4*)out)[i] = o;
  }
}

// in: [R][C] fp32, out: [C][R] bf16
__global__ void transpose_cvt(const float* __restrict__ in,
                              unsigned short* __restrict__ out, int R, int C) {
  __shared__ float tile[32][33];
  int c0 = blockIdx.x * 32, r0 = blockIdx.y * 32;
  int tx = threadIdx.x, ty = threadIdx.y;
#pragma unroll
  for (int i = 0; i < 4; i++)
    tile[ty + i * 8][tx] = in[(size_t)(r0 + ty + i * 8) * C + c0 + tx];
  __syncthreads();
#pragma unroll
  for (int i = 0; i < 4; i++)
    out[(size_t)(c0 + ty + i * 8) * R + r0 + tx] = f2bf(tile[tx][ty + i * 8]);
}

// ---------------------------------------------------------------------------
// QKV GEMM: C[4096][6144] = xb[4096][2048] @ WqkvT[6144][2048]^T  (+bias)
// 256x256 tile, BK=32, 8 waves (2x4), 4-buffer depth-3 pipeline, 128KB LDS.
// Per-wave output 128x64 (8 m-frags x 4 n-frags).  n-frags interleaved
// {f, f+1, f+4, f+5} so RoPE pairs (d, d+64) live in the same wave.
// Fused epilogue: RoPE on q,k (q pre-scaled by log2e/sqrt(128)),
// V stored transposed [b][h][d][s] via full-LDS transpose.
// ---------------------------------------------------------------------------
__global__ __launch_bounds__(512, 2) void qkv_gemm(
    const unsigned short* __restrict__ A,   // xb [4096][2048]
    const unsigned short* __restrict__ Bt,  // WqkvT [6144][2048]
    const float* __restrict__ bias,         // [6144]
    unsigned short* __restrict__ Qo,        // [2][16][2048][128]
    unsigned short* __restrict__ Ko,        // [2][16][2048][128]
    unsigned short* __restrict__ Vo)        // [2][16][128][2048]
{
  __shared__ __align__(16) unsigned short SH[65536];   // 128 KB
  // A bufs: SH + buf*8192 (256 rows x 32 k);  B bufs: SH + 32768 + buf*8192

  const int NWG = 384;
  int bid = blockIdx.x;
  int nid = (bid & 7) * (NWG / 8) + (bid >> 3);   // XCD-bijective swizzle
  int by = nid / 24, bx = nid - by * 24;

  int tid = threadIdx.x;
  int wv = tid >> 6, lane = tid & 63;
  int wr = wv >> 2, wc = wv & 3;
  int g = lane >> 4, c = lane & 15;

  int m0 = by * 256, n0 = bx * 256;

  // interleaved n-frag map: {8*lh+2*j, +1, +4, +5}
  int lh = wc >> 1, jj = wc & 1;
  int F[4];
#pragma unroll
  for (int n = 0; n < 4; n++) F[n] = 8 * lh + 2 * jj + (n & 1) + ((n >> 1) << 2);

  f32x4 acc[8][4];
#pragma unroll
  for (int m = 0; m < 8; m++)
#pragma unroll
    for (int n = 0; n < 4; n++)
#pragma unroll
      for (int r = 0; r < 4; r++) acc[m][n][r] = 0.f;

  // stage one BK=32 K-tile (4 gl_lds16 per thread: A x2, B x2)
  auto stage = [&](int buf, int kt) {
    int k0 = kt * 32;
    unsigned short* Ad = SH + buf * 8192;
    unsigned short* Bd = SH + 32768 + buf * 8192;
#pragma unroll
    for (int p = 0; p < 2; p++) {
      int e = p * 512 + tid;
      int row = e >> 2, sl = (e & 3) ^ ((row >> 1) & 3);   // pre-swizzled src
      gl_lds16(A  + (size_t)(m0 + row) * 2048 + k0 + sl * 8,
               Ad + p * 4096 + wv * 512);
      gl_lds16(Bt + (size_t)(n0 + row) * 2048 + k0 + sl * 8,
               Bd + p * 4096 + wv * 512);
    }
  };

  stage(0, 0); stage(1, 1); stage(2, 2);   // 12 loads/thread in flight

  for (int t = 0; t < 64; t++) {
    if (t < 62)       asm volatile("s_waitcnt vmcnt(8)" ::: "memory");
    else if (t == 62) asm volatile("s_waitcnt vmcnt(4)" ::: "memory");
    else              asm volatile("s_waitcnt vmcnt(0)" ::: "memory");
    __builtin_amdgcn_s_barrier();          // raw: no vmcnt(0) auto-drain

    const unsigned short* Ab = SH + (t & 3) * 8192;
    const unsigned short* Bb = SH + 32768 + (t & 3) * 8192;

    short8 af[8], bfv[4];
#pragma unroll
    for (int m = 0; m < 8; m++) {
      int row = wr * 128 + m * 16 + c;
      af[m] = *(const short8*)(Ab + row * 32 + ((g ^ ((row >> 1) & 3)) << 3));
    }
#pragma unroll
    for (int n = 0; n < 4; n++) {
      int row = F[n] * 16 + c;
      bfv[n] = *(const short8*)(Bb + row * 32 + ((g ^ ((row >> 1) & 3)) << 3));
    }

    if (t < 61) stage((t + 3) & 3, t + 3);   // prefetch depth-3

    __builtin_amdgcn_s_setprio(1);
#pragma unroll
    for (int m = 0; m < 8; m++)
#pragma unroll
      for (int n = 0; n < 4; n++)
        MFMA16(acc[m][n], af[m], bfv[n]);
    __builtin_amdgcn_s_setprio(0);
  }

  int sel = bx >> 3;        // 0=q 1=k 2=v  (8 bx per region)
  int bxl = bx & 7;
  int b = by >> 3;

  float biasv[4];
#pragma unroll
  for (int n = 0; n < 4; n++) biasv[n] = bias[n0 + F[n] * 16 + c];

  if (sel == 2) {
    // V: full-LDS transpose (swizzled) then coalesced store to Vo[b][h][d][s]
    __syncthreads();                      // all K-loop LDS reads done
    unsigned short* Vs = SH;              // 256 d' x 256 s = 128 KB
#pragma unroll
    for (int m = 0; m < 8; m++)
#pragma unroll
      for (int n = 0; n < 4; n++) {
        int dp = F[n] * 16 + c;
        int sb = wr * 128 + m * 16 + 4 * g;
        us4 pk;
#pragma unroll
        for (int r = 0; r < 4; r++) pk[r] = f2bf(acc[m][n][r] + biasv[n]);
        *(us4*)(Vs + dp * 256 + (sb ^ ((dp & 7) << 3))) = pk;
      }
    __syncthreads();
#pragma unroll
    for (int it = 0; it < 16; it++) {
      int u = it * 512 + tid;
      int dp = u >> 5, ch = u & 31;
      short8 val = *(const short8*)(Vs + dp * 256 + ((ch ^ (dp & 7)) << 3));
      int head = bxl * 2 + (dp >> 7), d = dp & 127;
      int sg = (by & 7) * 256 + ch * 8;
      *(short8*)(Vo + ((size_t)((b * 16 + head) * 128 + d)) * 2048 + sg) = val;
    }
  } else {
    // q / k: RoPE epilogue
    unsigned short* outp = (sel == 0) ? Qo : Ko;
    // q pre-scaled by log2(e)/sqrt(128) so attention softmax runs in exp2 domain
    float qscale = (sel == 0) ? (0.08838834764831845f * 1.44269504088896340736f) : 1.0f;
    int head = bxl * 2 + lh;
    float invf[2];
#pragma unroll
    for (int j = 0; j < 2; j++)
      invf[j] = __expf(-(float)((2 * jj + j) * 16 + c) * 0.14391156831212787f);
#pragma unroll
    for (int m = 0; m < 8; m++) {
#pragma unroll
      for (int j = 0; j < 2; j++) {
        int dlo = (2 * jj + j) * 16 + c;
#pragma unroll
        for (int r = 0; r < 4; r++) {
          int s_seq = (by & 7) * 256 + wr * 128 + m * 16 + 4 * g + r;
          float ang = (float)s_seq * invf[j];
          float sn, cs;
          __sincosf(ang, &sn, &cs);
          float vlo = acc[m][j][r]     + biasv[j];
          float vhi = acc[m][j + 2][r] + biasv[j + 2];
          float rlo = (vlo * cs - vhi * sn) * qscale;
          float rhi = (vhi * cs + vlo * sn) * qscale;
          size_t base = ((size_t)((b * 16 + head) * 2048 + s_seq)) * 128;
          outp[base + dlo]      = f2bf(rlo);
          outp[base + dlo + 64] = f2bf(rhi);
        }
      }
    }
  }
}

// ---------------------------------------------------------------------------
// Flash attention: per block one (b,h) x 128 q-rows; 4 waves x 32 q-rows.
// KVBLK=64, double-buffered K/V staging, swapped QK^T, exp2-domain softmax.
// ---------------------------------------------------------------------------
__global__ __launch_bounds__(256, 2) void attn_kernel(
    const unsigned short* __restrict__ Qi,   // [32][2048][128]
    const unsigned short* __restrict__ Ki,   // [32][2048][128]
    const unsigned short* __restrict__ Vi,   // [32][128][2048]
    unsigned short* __restrict__ X2)         // [4096][2048] bf16
{
  __shared__ __align__(16) unsigned short Kl[2][64 * 128];   // [s][d], swizzled
  __shared__ __align__(16) unsigned short Vl[2][128 * 64];   // [d][s], swizzled
  __shared__ __align__(16) unsigned short Pl[4][32 * 64];    // per-wave [q][k], swizzled

  int bid = blockIdx.x;
  int nid = (bid & 7) * 64 + (bid >> 3);   // XCD swizzle: 4 heads' KV per L2
  int bh = nid >> 4, qblk = nid & 15;
  int tid = threadIdx.x, wv = tid >> 6, lane = tid & 63;
  int g = lane >> 4, c = lane & 15;

  const unsigned short* Kg = Ki + (size_t)bh * 2048 * 128;
  const unsigned short* Vg = Vi + (size_t)bh * 128 * 2048;
  const unsigned short* Qb = Qi + ((size_t)bh * 2048 + qblk * 128 + wv * 32) * 128;

  short8 qf[2][4];
#pragma unroll
  for (int qt = 0; qt < 2; qt++)
#pragma unroll
    for (int dc = 0; dc < 4; dc++)
      qf[qt][dc] = *(const short8*)(Qb + (size_t)(qt * 16 + c) * 128 + dc * 32 + g * 8);

  f32x4 accO[2][8];
#pragma unroll
  for (int qt = 0; qt < 2; qt++)
#pragma unroll
    for (int nt = 0; nt < 8; nt++)
#pragma unroll
      for (int r = 0; r < 4; r++) accO[qt][nt][r] = 0.f;
  float m_run[2] = {-3.0e38f, -3.0e38f};
  float l_run[2] = {0.f, 0.f};

  auto stage = [&](int bsel, int t0) {
#pragma unroll
    for (int j = 0; j < 4; j++) {
      int e = j * 256 + tid;              // 0..1023
      int s = e >> 4, sl = e & 15;        // K row / 16B slot
      gl_lds16(Kg + (size_t)(t0 + s) * 128 + ((sl ^ (s & 7)) * 8),
               &Kl[bsel][(size_t)(j * 256 + wv * 64) * 8]);
    }
#pragma unroll
    for (int j = 0; j < 4; j++) {
      int e = j * 256 + tid;
      int d = e >> 3, sl = e & 7;         // V row / 16B slot
      gl_lds16(Vg + (size_t)d * 2048 + t0 + ((sl ^ (d & 7)) * 8),
               &Vl[bsel][(size_t)(j * 256 + wv * 64) * 8]);
    }
  };

  stage(0, 0);
  __syncthreads();

  int cur = 0;
  for (int t = 0; t < 32; t++) {
    if (t < 31) stage(cur ^ 1, (t + 1) * 64);   // prefetch next tile

    const unsigned short* Kt_ = &Kl[cur][0];
    const unsigned short* Vt_ = &Vl[cur][0];
    unsigned short* Pw = &Pl[wv][0];

    f32x4 sc[2][4];
#pragma unroll
    for (int qt = 0; qt < 2; qt++)
#pragma unroll
      for (int kt = 0; kt < 4; kt++)
#pragma unroll
        for (int r = 0; r < 4; r++) sc[qt][kt][r] = 0.f;

#pragma unroll
    for (int kt = 0; kt < 4; kt++) {
      short8 kf[4];
#pragma unroll
      for (int dc = 0; dc < 4; dc++)
        kf[dc] = *(const short8*)(Kt_ + (size_t)(kt * 16 + c) * 128 +
                                  (((dc * 4 + g) ^ (c & 7)) * 8));
      __builtin_amdgcn_s_setprio(1);
#pragma unroll
      for (int dc = 0; dc < 4; dc++) {
        MFMA16(sc[0][kt], kf[dc], qf[0][dc]);
        MFMA16(sc[1][kt], kf[dc], qf[1][dc]);
      }
      __builtin_amdgcn_s_setprio(0);
    }

    float mx[2];
#pragma unroll
    for (int qt = 0; qt < 2; qt++) {
      f32x4 mv = sc[qt][0];
#pragma unroll
      for (int kt = 1; kt < 4; kt++)
#pragma unroll
        for (int r = 0; r < 4; r++) mv[r] = fmaxf(mv[r], sc[qt][kt][r]);
      float m0 = fmaxf(fmaxf(mv[0], mv[1]), fmaxf(mv[2], mv[3]));
      m0 = fmaxf(m0, __shfl_xor(m0, 16));
      m0 = fmaxf(m0, __shfl_xor(m0, 32));
      mx[qt] = m0;
    }
    if (__any((mx[0] > m_run[0]) || (mx[1] > m_run[1]))) {
#pragma unroll
      for (int qt = 0; qt < 2; qt++) {
        float mnew = fmaxf(m_run[qt], mx[qt]);
        float al = __builtin_exp2f(m_run[qt] - mnew);
        l_run[qt] *= al;
        m_run[qt] = mnew;
#pragma unroll
        for (int r = 0; r < 4; r++) {
          float alr = __shfl(al, 4 * g + r);
#pragma unroll
          for (int nt = 0; nt < 8; nt++) accO[qt][nt][r] *= alr;
        }
      }
    }
#pragma unroll
    for (int qt = 0; qt < 2; qt++) {
      float rs = 0.f;
#pragma unroll
      for (int kt = 0; kt < 4; kt++) {
        float p0 = __builtin_exp2f(sc[qt][kt][0] - m_run[qt]);
        float p1 = __builtin_exp2f(sc[qt][kt][1] - m_run[qt]);
        float p2 = __builtin_exp2f(sc[qt][kt][2] - m_run[qt]);
        float p3 = __builtin_exp2f(sc[qt][kt][3] - m_run[qt]);
        rs += (p0 + p1) + (p2 + p3);
        unsigned int lo, hi;
        asm("v_cvt_pk_bf16_f32 %0, %1, %2" : "=v"(lo) : "v"(p0), "v"(p1));
        asm("v_cvt_pk_bf16_f32 %0, %1, %2" : "=v"(hi) : "v"(p2), "v"(p3));
        uint2 pk; pk.x = lo; pk.y = hi;
        *(uint2*)(Pw + (size_t)(qt * 16 + c) * 64 +
                  (((kt * 2 + (g >> 1)) ^ (c & 7)) * 8) + (g & 1) * 4) = pk;
      }
      rs += __shfl_xor(rs, 16);
      rs += __shfl_xor(rs, 32);
      l_run[qt] += rs;
    }

    short8 pa[2][2];
#pragma unroll
    for (int qt = 0; qt < 2; qt++)
#pragma unroll
      for (int kc = 0; kc < 2; kc++)
        pa[qt][kc] = *(const short8*)(Pw + (size_t)(qt * 16 + c) * 64 +
                                      (((kc * 4 + g) ^ (c & 7)) * 8));
#pragma unroll
    for (int nt = 0; nt < 8; nt++) {
      short8 vf0 = *(const short8*)(Vt_ + (size_t)(nt * 16 + c) * 64 +
                                    ((g ^ (c & 7)) * 8));
      short8 vf1 = *(const short8*)(Vt_ + (size_t)(nt * 16 + c) * 64 +
                                    (((4 + g) ^ (c & 7)) * 8));
      __builtin_amdgcn_s_setprio(1);
      MFMA16(accO[0][nt], pa[0][0], vf0);
      MFMA16(accO[1][nt], pa[1][0], vf0);
      MFMA16(accO[0][nt], pa[0][1], vf1);
      MFMA16(accO[1][nt], pa[1][1], vf1);
      __builtin_amdgcn_s_setprio(0);
    }

    __syncthreads();
    cur ^= 1;
  }

  float rl[2] = {1.f / l_run[0], 1.f / l_run[1]};
  int b = bh >> 4, h = bh & 15;
  size_t rowbase = (size_t)b * 2048 + qblk * 128 + wv * 32;
#pragma unroll
  for (int qt = 0; qt < 2; qt++)
#pragma unroll
    for (int r = 0; r < 4; r++) {
      float rr = __shfl(rl[qt], 4 * g + r);
      size_t row = rowbase + qt * 16 + 4 * g + r;
#pragma unroll
      for (int nt = 0; nt < 8; nt++)
        X2[row * 2048 + h * 128 + nt * 16 + c] = f2bf(accO[qt][nt][r] * rr);
    }
}

// ---------------------------------------------------------------------------
// Proj GEMM: out[4096][2048] = x2[4096][2048] @ WprojT[2048][2048]^T + bias
// 256x128 tile, BK=32, 8 waves (4x2), 4-buffer depth-3 pipeline, 96KB LDS.
// Grid 256 = exactly 1 block/CU.
// ---------------------------------------------------------------------------
__global__ __launch_bounds__(512, 2) void proj_gemm(
    const unsigned short* __restrict__ A,
    const unsigned short* __restrict__ Bt,
    const float* __restrict__ bias,
    float* __restrict__ Co)
{
  __shared__ __align__(16) unsigned short SH[49152];   // 96 KB
  // A bufs: SH + buf*8192 (256x32);  B bufs: SH + 32768 + buf*4096 (128x32)

  int bid = blockIdx.x;
  int nid = (bid & 7) * 32 + (bid >> 3);
  int by = nid >> 4, bx = nid & 15;

  int tid = threadIdx.x;
  int wv = tid >> 6, lane = tid & 63;
  int wr = wv >> 1, wc = wv & 1;
  int g = lane >> 4, c = lane & 15;

  int m0 = by * 256, n0 = bx * 128;

  f32x4 acc[4][4];
#pragma unroll
  for (int m = 0; m < 4; m++)
#pragma unroll
    for (int n = 0; n < 4; n++)
#pragma unroll
      for (int r = 0; r < 4; r++) acc[m][n][r] = 0.f;

  auto stage = [&](int buf, int kt) {
    int k0 = kt * 32;
    unsigned short* Ad = SH + buf * 8192;
    unsigned short* Bd = SH + 32768 + buf * 4096;
#pragma unroll
    for (int p = 0; p < 2; p++) {
      int e = p * 512 + tid;
      int row = e >> 2, sl = (e & 3) ^ ((row >> 1) & 3);
      gl_lds16(A + (size_t)(m0 + row) * 2048 + k0 + sl * 8,
               Ad + p * 4096 + wv * 512);
    }
    {
      int e = tid;
      int row = e >> 2, sl = (e & 3) ^ ((row >> 1) & 3);
      gl_lds16(Bt + (size_t)(n0 + row) * 2048 + k0 + sl * 8,
               Bd + wv * 512);
    }
  };

  stage(0, 0); stage(1, 1); stage(2, 2);   // 9 loads/thread in flight

  for (int t = 0; t < 64; t++) {
    if (t < 62)       asm volatile("s_waitcnt vmcnt(6)" ::: "memory");
    else if (t == 62) asm volatile("s_waitcnt vmcnt(3)" ::: "memory");
    else              asm volatile("s_waitcnt vmcnt(0)" ::: "memory");
    __builtin_amdgcn_s_barrier();

    const unsigned short* Ab = SH + (t & 3) * 8192;
    const unsigned short* Bb = SH + 32768 + (t & 3) * 4096;

    short8 af[4], bfv[4];
#pragma unroll
    for (int m = 0; m < 4; m++) {
      int row = wr * 64 + m * 16 + c;
      af[m] = *(const short8*)(Ab + row * 32 + ((g ^ ((row >> 1) & 3)) << 3));
    }
#pragma unroll
    for (int n = 0; n < 4; n++) {
      int row = (wc * 4 + n) * 16 + c;
      bfv[n] = *(const short8*)(Bb + row * 32 + ((g ^ ((row >> 1) & 3)) << 3));
    }

    if (t < 61) stage((t + 3) & 3, t + 3);

    __builtin_amdgcn_s_setprio(1);
#pragma unroll
    for (int m = 0; m < 4; m++)
#pragma unroll
      for (int n = 0; n < 4; n++)
        MFMA16(acc[m][n], af[m], bfv[n]);
    __builtin_amdgcn_s_setprio(0);
  }

#pragma unroll
  for (int m = 0; m < 4; m++)
#pragma unroll
    for (int n = 0; n < 4; n++)
#pragma unroll
      for (int r = 0; r < 4; r++) {
        int row = m0 + wr * 64 + m * 16 + 4 * g + r;
        int col = n0 + wc * 64 + n * 16 + c;
        Co[(size_t)row * 2048 + col] = acc[m][n][r] + bias[col];
      }
}

// ---------------------------------------------------------------------------
extern "C" void kernel_launch(void* const* d_in, const int* in_sizes, int n_in,
                              void* d_out, int out_size, void* d_ws, size_t ws_size,
                              hipStream_t stream) {
  (void)in_sizes; (void)n_in; (void)out_size; (void)ws_size;

  const float* x      = (const float*)d_in[0];   // [2][2048][2048]
  const float* W_qkv  = (const float*)d_in[1];   // [2048][6144]
  const float* b_qkv  = (const float*)d_in[2];   // [6144]
  const float* W_proj = (const float*)d_in[3];   // [2048][2048]
  const float* b_proj = (const float*)d_in[4];   // [2048]
  float* out = (float*)d_out;                    // [4096][2048]

  // workspace layout (bf16 elements); total ~114 MB
  unsigned short* xb     = (unsigned short*)d_ws;     // 4096*2048
  unsigned short* wqkvT  = xb     + 8388608;          // 6144*2048
  unsigned short* wprojT = wqkvT  + 12582912;         // 2048*2048
  unsigned short* Qb     = wprojT + 4194304;          // 32*2048*128
  unsigned short* Kb     = Qb     + 8388608;
  unsigned short* Vtb    = Kb     + 8388608;          // [32][128][2048]
  unsigned short* x2     = Vtb    + 8388608;          // 4096*2048

  cvt_f32_bf16<<<2048, 256, 0, stream>>>(x, xb, 8388608 / 4);
  transpose_cvt<<<dim3(192, 64), dim3(32, 8), 0, stream>>>(W_qkv, wqkvT, 2048, 6144);
  transpose_cvt<<<dim3(64, 64),  dim3(32, 8), 0, stream>>>(W_proj, wprojT, 2048, 2048);
  qkv_gemm<<<384, 512, 0, stream>>>(xb, wqkvT, b_qkv, Qb, Kb, Vtb);
  attn_kernel<<<512, 256, 0, stream>>>(Qb, Kb, Vtb, x2);
  proj_gemm<<<256, 512, 0, stream>>>(x2, wprojT, b_proj, out);
}

// Round 7
// 392.727 us; speedup vs baseline: 1.0178x; 1.0178x over previous
//
#include <hip/hip_runtime.h>

// ---------------------------------------------------------------------------
// SelfAttention block: x @ W_qkv -> RoPE(q,k) -> flash attention -> @ W_proj
// B=2, S=2048, D=2048, H=16, hd=128.  All matmuls in bf16 MFMA (fp32 accum).
// ---------------------------------------------------------------------------

typedef __attribute__((ext_vector_type(4))) float  f32x4;
typedef __attribute__((ext_vector_type(8))) short  short8;
typedef __attribute__((ext_vector_type(4))) float  fv4;
typedef __attribute__((ext_vector_type(4))) unsigned short us4;

#define MFMA16(accv, av, bv) \
  asm volatile("v_mfma_f32_16x16x32_bf16 %0, %1, %2, %0" : "+v"(accv) : "v"(av), "v"(bv))

__device__ __forceinline__ unsigned short f2bf(float f) {
  unsigned int u = __float_as_uint(f);
  u += 0x7fffu + ((u >> 16) & 1u);      // round-to-nearest-even
  return (unsigned short)(u >> 16);
}

__device__ __forceinline__ void gl_lds16(const void* g, void* l) {
  // async global->LDS, 16B per lane; LDS dest = uniform base + lane*16
  __builtin_amdgcn_global_load_lds((const __attribute__((address_space(1))) void*)g,
                                   (__attribute__((address_space(3))) void*)l, 16, 0, 0);
}

// ---------------------------------------------------------------------------
// Prep: fp32 -> bf16 convert (x), and fp32 -> transposed bf16 (weights)
// ---------------------------------------------------------------------------
__global__ void cvt_f32_bf16(const float* __restrict__ in,
                             unsigned short* __restrict__ out, int n4) {
  int i = blockIdx.x * blockDim.x + threadIdx.x;
  int stride = gridDim.x * blockDim.x;
  for (; i < n4; i += stride) {
    fv4 v = ((const fv4*)in)[i];
    us4 o;
    o[0] = f2bf(v[0]); o[1] = f2bf(v[1]); o[2] = f2bf(v[2]); o[3] = f2bf(v[3]);
    ((us4*)out)[i] = o;
  }
}

// in: [R][C] fp32, out: [C][R] bf16
__global__ void transpose_cvt(const float* __restrict__ in,
                              unsigned short* __restrict__ out, int R, int C) {
  __shared__ float tile[32][33];
  int c0 = blockIdx.x * 32, r0 = blockIdx.y * 32;
  int tx = threadIdx.x, ty = threadIdx.y;
#pragma unroll
  for (int i = 0; i < 4; i++)
    tile[ty + i * 8][tx] = in[(size_t)(r0 + ty + i * 8) * C + c0 + tx];
  __syncthreads();
#pragma unroll
  for (int i = 0; i < 4; i++)
    out[(size_t)(c0 + ty + i * 8) * R + r0 + tx] = f2bf(tile[tx][ty + i * 8]);
}

// ---------------------------------------------------------------------------
// QKV GEMM: C[4096][6144] = xb[4096][2048] @ WqkvT[6144][2048]^T  (+bias)
// 256x256 tile, BK=32, 8 waves (2x4), 4-buffer depth-3 pipeline, 128KB LDS.
// (unchanged from round 6)
// ---------------------------------------------------------------------------
__global__ __launch_bounds__(512, 2) void qkv_gemm(
    const unsigned short* __restrict__ A,   // xb [4096][2048]
    const unsigned short* __restrict__ Bt,  // WqkvT [6144][2048]
    const float* __restrict__ bias,         // [6144]
    unsigned short* __restrict__ Qo,        // [2][16][2048][128]
    unsigned short* __restrict__ Ko,        // [2][16][2048][128]
    unsigned short* __restrict__ Vo)        // [2][16][128][2048]
{
  __shared__ __align__(16) unsigned short SH[65536];   // 128 KB

  const int NWG = 384;
  int bid = blockIdx.x;
  int nid = (bid & 7) * (NWG / 8) + (bid >> 3);   // XCD-bijective swizzle
  int by = nid / 24, bx = nid - by * 24;

  int tid = threadIdx.x;
  int wv = tid >> 6, lane = tid & 63;
  int wr = wv >> 2, wc = wv & 3;
  int g = lane >> 4, c = lane & 15;

  int m0 = by * 256, n0 = bx * 256;

  int lh = wc >> 1, jj = wc & 1;
  int F[4];
#pragma unroll
  for (int n = 0; n < 4; n++) F[n] = 8 * lh + 2 * jj + (n & 1) + ((n >> 1) << 2);

  f32x4 acc[8][4];
#pragma unroll
  for (int m = 0; m < 8; m++)
#pragma unroll
    for (int n = 0; n < 4; n++)
#pragma unroll
      for (int r = 0; r < 4; r++) acc[m][n][r] = 0.f;

  auto stage = [&](int buf, int kt) {
    int k0 = kt * 32;
    unsigned short* Ad = SH + buf * 8192;
    unsigned short* Bd = SH + 32768 + buf * 8192;
#pragma unroll
    for (int p = 0; p < 2; p++) {
      int e = p * 512 + tid;
      int row = e >> 2, sl = (e & 3) ^ ((row >> 1) & 3);
      gl_lds16(A  + (size_t)(m0 + row) * 2048 + k0 + sl * 8,
               Ad + p * 4096 + wv * 512);
      gl_lds16(Bt + (size_t)(n0 + row) * 2048 + k0 + sl * 8,
               Bd + p * 4096 + wv * 512);
    }
  };

  stage(0, 0); stage(1, 1); stage(2, 2);

  for (int t = 0; t < 64; t++) {
    if (t < 62)       asm volatile("s_waitcnt vmcnt(8)" ::: "memory");
    else if (t == 62) asm volatile("s_waitcnt vmcnt(4)" ::: "memory");
    else              asm volatile("s_waitcnt vmcnt(0)" ::: "memory");
    __builtin_amdgcn_s_barrier();

    const unsigned short* Ab = SH + (t & 3) * 8192;
    const unsigned short* Bb = SH + 32768 + (t & 3) * 8192;

    short8 af[8], bfv[4];
#pragma unroll
    for (int m = 0; m < 8; m++) {
      int row = wr * 128 + m * 16 + c;
      af[m] = *(const short8*)(Ab + row * 32 + ((g ^ ((row >> 1) & 3)) << 3));
    }
#pragma unroll
    for (int n = 0; n < 4; n++) {
      int row = F[n] * 16 + c;
      bfv[n] = *(const short8*)(Bb + row * 32 + ((g ^ ((row >> 1) & 3)) << 3));
    }

    if (t < 61) stage((t + 3) & 3, t + 3);

    __builtin_amdgcn_s_setprio(1);
#pragma unroll
    for (int m = 0; m < 8; m++)
#pragma unroll
      for (int n = 0; n < 4; n++)
        MFMA16(acc[m][n], af[m], bfv[n]);
    __builtin_amdgcn_s_setprio(0);
  }

  int sel = bx >> 3;
  int bxl = bx & 7;
  int b = by >> 3;

  float biasv[4];
#pragma unroll
  for (int n = 0; n < 4; n++) biasv[n] = bias[n0 + F[n] * 16 + c];

  if (sel == 2) {
    __syncthreads();
    unsigned short* Vs = SH;
#pragma unroll
    for (int m = 0; m < 8; m++)
#pragma unroll
      for (int n = 0; n < 4; n++) {
        int dp = F[n] * 16 + c;
        int sb = wr * 128 + m * 16 + 4 * g;
        us4 pk;
#pragma unroll
        for (int r = 0; r < 4; r++) pk[r] = f2bf(acc[m][n][r] + biasv[n]);
        *(us4*)(Vs + dp * 256 + (sb ^ ((dp & 7) << 3))) = pk;
      }
    __syncthreads();
#pragma unroll
    for (int it = 0; it < 16; it++) {
      int u = it * 512 + tid;
      int dp = u >> 5, ch = u & 31;
      short8 val = *(const short8*)(Vs + dp * 256 + ((ch ^ (dp & 7)) << 3));
      int head = bxl * 2 + (dp >> 7), d = dp & 127;
      int sg = (by & 7) * 256 + ch * 8;
      *(short8*)(Vo + ((size_t)((b * 16 + head) * 128 + d)) * 2048 + sg) = val;
    }
  } else {
    unsigned short* outp = (sel == 0) ? Qo : Ko;
    float qscale = (sel == 0) ? (0.08838834764831845f * 1.44269504088896340736f) : 1.0f;
    int head = bxl * 2 + lh;
    float invf[2];
#pragma unroll
    for (int j = 0; j < 2; j++)
      invf[j] = __expf(-(float)((2 * jj + j) * 16 + c) * 0.14391156831212787f);
#pragma unroll
    for (int m = 0; m < 8; m++) {
#pragma unroll
      for (int j = 0; j < 2; j++) {
        int dlo = (2 * jj + j) * 16 + c;
#pragma unroll
        for (int r = 0; r < 4; r++) {
          int s_seq = (by & 7) * 256 + wr * 128 + m * 16 + 4 * g + r;
          float ang = (float)s_seq * invf[j];
          float sn, cs;
          __sincosf(ang, &sn, &cs);
          float vlo = acc[m][j][r]     + biasv[j];
          float vhi = acc[m][j + 2][r] + biasv[j + 2];
          float rlo = (vlo * cs - vhi * sn) * qscale;
          float rhi = (vhi * cs + vlo * sn) * qscale;
          size_t base = ((size_t)((b * 16 + head) * 2048 + s_seq)) * 128;
          outp[base + dlo]      = f2bf(rlo);
          outp[base + dlo + 64] = f2bf(rhi);
        }
      }
    }
  }
}

// ---------------------------------------------------------------------------
// Flash attention v3: 128 q-rows/block, 4 waves x 32 q; KVBLK=64, double-buf.
// Swapped QK^T, exp2-domain.  NEW: all LDS addresses hoisted to loop-invariant
// bases + XOR/immediate offsets; defer-max (THR=8, exp2 units) skips the max
// reduce + rescale in the common case; l_run is a per-lane partial, reduced
// once in the epilogue.
// ---------------------------------------------------------------------------
__global__ __launch_bounds__(256, 2) void attn_kernel(
    const unsigned short* __restrict__ Qi,   // [32][2048][128]
    const unsigned short* __restrict__ Ki,   // [32][2048][128]
    const unsigned short* __restrict__ Vi,   // [32][128][2048]
    unsigned short* __restrict__ X2)         // [4096][2048] bf16
{
  __shared__ __align__(16) unsigned short Kl[2][64 * 128];   // [s][d], swizzled
  __shared__ __align__(16) unsigned short Vl[2][128 * 64];   // [d][s], swizzled
  __shared__ __align__(16) unsigned short Pl[4][32 * 64];    // per-wave [q][k], swizzled

  int bid = blockIdx.x;
  int nid = (bid & 7) * 64 + (bid >> 3);   // XCD swizzle
  int bh = nid >> 4, qblk = nid & 15;
  int tid = threadIdx.x, wv = tid >> 6, lane = tid & 63;
  int g = lane >> 4, c = lane & 15;

  const unsigned short* Kg = Ki + (size_t)bh * 2048 * 128;
  const unsigned short* Vg = Vi + (size_t)bh * 128 * 2048;
  const unsigned short* Qb = Qi + ((size_t)bh * 2048 + qblk * 128 + wv * 32) * 128;

  short8 qf[2][4];
#pragma unroll
  for (int qt = 0; qt < 2; qt++)
#pragma unroll
    for (int dc = 0; dc < 4; dc++)
      qf[qt][dc] = *(const short8*)(Qb + (size_t)(qt * 16 + c) * 128 + dc * 32 + g * 8);

  f32x4 accO[2][8];
#pragma unroll
  for (int qt = 0; qt < 2; qt++)
#pragma unroll
    for (int nt = 0; nt < 8; nt++)
#pragma unroll
      for (int r = 0; r < 4; r++) accO[qt][nt][r] = 0.f;
  float m_run[2] = {-3.0e38f, -3.0e38f};
  float l_run[2] = {0.f, 0.f};     // per-lane partial (reduced over g at end)

  // ---- hoisted LDS ushort-offsets (verified bit-disjoint decompositions) ----
  int cb2  = (c >> 2) & 1;
  int gl2  = g ^ (c & 3);
  // K frag: slot (4dc+g)^(c&7) -> base; dc&1 -> ^32, dc>>1 -> +64, kt -> +2048
  int koff  = c * 128 + gl2 * 8 + cb2 * 32;
  int koffx = koff ^ 32;
  // V frag: slot (4vh+g)^(c&7) (vh=0/1) -> base / ^32; nt -> +1024
  int voff  = c * 64 + gl2 * 8 + cb2 * 32;
  int voffx = voff ^ 32;
  // P write: ((2kt+(g>>1))^(c&7))*8 + (g&1)*4 -> base; kt -> ^(kt*16); qt -> +1024
  int pwoff = c * 64 + (((g >> 1) ^ (c & 1)) * 8) + (g & 1) * 4 + (((c >> 1) & 3) * 16);
  // P read: slot (4kc+g)^(c&7) -> base; kc -> ^32; qt -> +1024
  int proff  = c * 64 + gl2 * 8 + cb2 * 32;
  int proffx = proff ^ 32;
  unsigned short* Pw = &Pl[wv][0];

  auto stage = [&](int bsel, int t0) {
#pragma unroll
    for (int j = 0; j < 4; j++) {
      int e = j * 256 + tid;
      int s = e >> 4, sl = e & 15;
      gl_lds16(Kg + (size_t)(t0 + s) * 128 + ((sl ^ (s & 7)) * 8),
               &Kl[bsel][(size_t)(j * 256 + wv * 64) * 8]);
    }
#pragma unroll
    for (int j = 0; j < 4; j++) {
      int e = j * 256 + tid;
      int d = e >> 3, sl = e & 7;
      gl_lds16(Vg + (size_t)d * 2048 + t0 + ((sl ^ (d & 7)) * 8),
               &Vl[bsel][(size_t)(j * 256 + wv * 64) * 8]);
    }
  };

  stage(0, 0);
  __syncthreads();

  int cur = 0;
  for (int t = 0; t < 32; t++) {
    if (t < 31) stage(cur ^ 1, (t + 1) * 64);   // prefetch next tile

    const unsigned short* Kt_ = &Kl[cur][0];
    const unsigned short* Vt_ = &Vl[cur][0];

    // ---- QK^T (swapped): sc[qt][kt] = S[k=kt*16+4g+r][q=qt*16+c] ----
    f32x4 sc[2][4];
#pragma unroll
    for (int qt = 0; qt < 2; qt++)
#pragma unroll
      for (int kt = 0; kt < 4; kt++)
#pragma unroll
        for (int r = 0; r < 4; r++) sc[qt][kt][r] = 0.f;

#pragma unroll
    for (int kt = 0; kt < 4; kt++) {
      short8 kf[4];
      kf[0] = *(const short8*)(Kt_ + koff  + kt * 2048);
      kf[1] = *(const short8*)(Kt_ + koffx + kt * 2048);
      kf[2] = *(const short8*)(Kt_ + koff  + 64 + kt * 2048);
      kf[3] = *(const short8*)(Kt_ + koffx + 64 + kt * 2048);
      __builtin_amdgcn_s_setprio(1);
#pragma unroll
      for (int dc = 0; dc < 4; dc++) {
        MFMA16(sc[0][kt], kf[dc], qf[0][dc]);
        MFMA16(sc[1][kt], kf[dc], qf[1][dc]);
      }
      __builtin_amdgcn_s_setprio(0);
    }

    // ---- online softmax, defer-max THR=8 (exp2 units) ----
    float mx[2];
#pragma unroll
    for (int qt = 0; qt < 2; qt++) {
      f32x4 mv = sc[qt][0];
#pragma unroll
      for (int kt = 1; kt < 4; kt++)
#pragma unroll
        for (int r = 0; r < 4; r++) mv[r] = fmaxf(mv[r], sc[qt][kt][r]);
      mx[qt] = fmaxf(fmaxf(mv[0], mv[1]), fmaxf(mv[2], mv[3]));   // per-lane partial
    }
    int grow = (mx[0] > m_run[0] + 8.f) | (mx[1] > m_run[1] + 8.f);
    if (__any(grow)) {
#pragma unroll
      for (int qt = 0; qt < 2; qt++) {
        float mm = mx[qt];
        mm = fmaxf(mm, __shfl_xor(mm, 16));
        mm = fmaxf(mm, __shfl_xor(mm, 32));
        float mnew = fmaxf(m_run[qt], mm);
        float al = __builtin_exp2f(m_run[qt] - mnew);
        l_run[qt] *= al;
        m_run[qt] = mnew;
#pragma unroll
        for (int r = 0; r < 4; r++) {
          float alr = __shfl(al, 4 * g + r);
#pragma unroll
          for (int nt = 0; nt < 8; nt++) accO[qt][nt][r] *= alr;
        }
      }
    }
#pragma unroll
    for (int qt = 0; qt < 2; qt++) {
      float rs = 0.f;
#pragma unroll
      for (int kt = 0; kt < 4; kt++) {
        float p0 = __builtin_exp2f(sc[qt][kt][0] - m_run[qt]);
        float p1 = __builtin_exp2f(sc[qt][kt][1] - m_run[qt]);
        float p2 = __builtin_exp2f(sc[qt][kt][2] - m_run[qt]);
        float p3 = __builtin_exp2f(sc[qt][kt][3] - m_run[qt]);
        rs += (p0 + p1) + (p2 + p3);
        unsigned int lo, hi;
        asm("v_cvt_pk_bf16_f32 %0, %1, %2" : "=v"(lo) : "v"(p0), "v"(p1));
        asm("v_cvt_pk_bf16_f32 %0, %1, %2" : "=v"(hi) : "v"(p2), "v"(p3));
        uint2 pk; pk.x = lo; pk.y = hi;
        *(uint2*)(Pw + (pwoff ^ (kt * 16)) + qt * 1024) = pk;
      }
      l_run[qt] += rs;       // per-lane partial; reduced in epilogue
    }

    // ---- PV ----
    short8 pa[2][2];
#pragma unroll
    for (int qt = 0; qt < 2; qt++) {
      pa[qt][0] = *(const short8*)(Pw + proff  + qt * 1024);
      pa[qt][1] = *(const short8*)(Pw + proffx + qt * 1024);
    }
#pragma unroll
    for (int nt = 0; nt < 8; nt++) {
      short8 vf0 = *(const short8*)(Vt_ + voff  + nt * 1024);
      short8 vf1 = *(const short8*)(Vt_ + voffx + nt * 1024);
      __builtin_amdgcn_s_setprio(1);
      MFMA16(accO[0][nt], pa[0][0], vf0);
      MFMA16(accO[1][nt], pa[1][0], vf0);
      MFMA16(accO[0][nt], pa[0][1], vf1);
      MFMA16(accO[1][nt], pa[1][1], vf1);
      __builtin_amdgcn_s_setprio(0);
    }

    __syncthreads();
    cur ^= 1;
  }

  // ---- epilogue: reduce l over g-groups, normalize, store ----
  float rl[2];
#pragma unroll
  for (int qt = 0; qt < 2; qt++) {
    float l = l_run[qt];
    l += __shfl_xor(l, 16);
    l += __shfl_xor(l, 32);
    rl[qt] = 1.0f / l;
  }
  int b = bh >> 4, h = bh & 15;
  size_t rowbase = (size_t)b * 2048 + qblk * 128 + wv * 32;
#pragma unroll
  for (int qt = 0; qt < 2; qt++)
#pragma unroll
    for (int r = 0; r < 4; r++) {
      float rr = __shfl(rl[qt], 4 * g + r);
      size_t row = rowbase + qt * 16 + 4 * g + r;
#pragma unroll
      for (int nt = 0; nt < 8; nt++)
        X2[row * 2048 + h * 128 + nt * 16 + c] = f2bf(accO[qt][nt][r] * rr);
    }
}

// ---------------------------------------------------------------------------
// Proj GEMM: out[4096][2048] = x2[4096][2048] @ WprojT[2048][2048]^T + bias
// (unchanged from round 6)
// ---------------------------------------------------------------------------
__global__ __launch_bounds__(512, 2) void proj_gemm(
    const unsigned short* __restrict__ A,
    const unsigned short* __restrict__ Bt,
    const float* __restrict__ bias,
    float* __restrict__ Co)
{
  __shared__ __align__(16) unsigned short SH[49152];   // 96 KB

  int bid = blockIdx.x;
  int nid = (bid & 7) * 32 + (bid >> 3);
  int by = nid >> 4, bx = nid & 15;

  int tid = threadIdx.x;
  int wv = tid >> 6, lane = tid & 63;
  int wr = wv >> 1, wc = wv & 1;
  int g = lane >> 4, c = lane & 15;

  int m0 = by * 256, n0 = bx * 128;

  f32x4 acc[4][4];
#pragma unroll
  for (int m = 0; m < 4; m++)
#pragma unroll
    for (int n = 0; n < 4; n++)
#pragma unroll
      for (int r = 0; r < 4; r++) acc[m][n][r] = 0.f;

  auto stage = [&](int buf, int kt) {
    int k0 = kt * 32;
    unsigned short* Ad = SH + buf * 8192;
    unsigned short* Bd = SH + 32768 + buf * 4096;
#pragma unroll
    for (int p = 0; p < 2; p++) {
      int e = p * 512 + tid;
      int row = e >> 2, sl = (e & 3) ^ ((row >> 1) & 3);
      gl_lds16(A + (size_t)(m0 + row) * 2048 + k0 + sl * 8,
               Ad + p * 4096 + wv * 512);
    }
    {
      int e = tid;
      int row = e >> 2, sl = (e & 3) ^ ((row >> 1) & 3);
      gl_lds16(Bt + (size_t)(n0 + row) * 2048 + k0 + sl * 8,
               Bd + wv * 512);
    }
  };

  stage(0, 0); stage(1, 1); stage(2, 2);

  for (int t = 0; t < 64; t++) {
    if (t < 62)       asm volatile("s_waitcnt vmcnt(6)" ::: "memory");
    else if (t == 62) asm volatile("s_waitcnt vmcnt(3)" ::: "memory");
    else              asm volatile("s_waitcnt vmcnt(0)" ::: "memory");
    __builtin_amdgcn_s_barrier();

    const unsigned short* Ab = SH + (t & 3) * 8192;
    const unsigned short* Bb = SH + 32768 + (t & 3) * 4096;

    short8 af[4], bfv[4];
#pragma unroll
    for (int m = 0; m < 4; m++) {
      int row = wr * 64 + m * 16 + c;
      af[m] = *(const short8*)(Ab + row * 32 + ((g ^ ((row >> 1) & 3)) << 3));
    }
#pragma unroll
    for (int n = 0; n < 4; n++) {
      int row = (wc * 4 + n) * 16 + c;
      bfv[n] = *(const short8*)(Bb + row * 32 + ((g ^ ((row >> 1) & 3)) << 3));
    }

    if (t < 61) stage((t + 3) & 3, t + 3);

    __builtin_amdgcn_s_setprio(1);
#pragma unroll
    for (int m = 0; m < 4; m++)
#pragma unroll
      for (int n = 0; n < 4; n++)
        MFMA16(acc[m][n], af[m], bfv[n]);
    __builtin_amdgcn_s_setprio(0);
  }

#pragma unroll
  for (int m = 0; m < 4; m++)
#pragma unroll
    for (int n = 0; n < 4; n++)
#pragma unroll
      for (int r = 0; r < 4; r++) {
        int row = m0 + wr * 64 + m * 16 + 4 * g + r;
        int col = n0 + wc * 64 + n * 16 + c;
        Co[(size_t)row * 2048 + col] = acc[m][n][r] + bias[col];
      }
}

// ---------------------------------------------------------------------------
extern "C" void kernel_launch(void* const* d_in, const int* in_sizes, int n_in,
                              void* d_out, int out_size, void* d_ws, size_t ws_size,
                              hipStream_t stream) {
  (void)in_sizes; (void)n_in; (void)out_size; (void)ws_size;

  const float* x      = (const float*)d_in[0];   // [2][2048][2048]
  const float* W_qkv  = (const float*)d_in[1];   // [2048][6144]
  const float* b_qkv  = (const float*)d_in[2];   // [6144]
  const float* W_proj = (const float*)d_in[3];   // [2048][2048]
  const float* b_proj = (const float*)d_in[4];   // [2048]
  float* out = (float*)d_out;                    // [4096][2048]

  // workspace layout (bf16 elements); total ~114 MB
  unsigned short* xb     = (unsigned short*)d_ws;     // 4096*2048
  unsigned short* wqkvT  = xb     + 8388608;          // 6144*2048
  unsigned short* wprojT = wqkvT  + 12582912;         // 2048*2048
  unsigned short* Qb     = wprojT + 4194304;          // 32*2048*128
  unsigned short* Kb     = Qb     + 8388608;
  unsigned short* Vtb    = Kb     + 8388608;          // [32][128][2048]
  unsigned short* x2     = Vtb    + 8388608;          // 4096*2048

  cvt_f32_bf16<<<2048, 256, 0, stream>>>(x, xb, 8388608 / 4);
  transpose_cvt<<<dim3(192, 64), dim3(32, 8), 0, stream>>>(W_qkv, wqkvT, 2048, 6144);
  transpose_cvt<<<dim3(64, 64),  dim3(32, 8), 0, stream>>>(W_proj, wprojT, 2048, 2048);
  qkv_gemm<<<384, 512, 0, stream>>>(xb, wqkvT, b_qkv, Qb, Kb, Vtb);
  attn_kernel<<<512, 256, 0, stream>>>(Qb, Kb, Vtb, x2);
  proj_gemm<<<256, 512, 0, stream>>>(x2, wprojT, b_proj, out);
}